// Round 1
// baseline (5865.240 us; speedup 1.0000x reference)
//
#include <hip/hip_runtime.h>
#include <stdint.h>

#define Bsz 512
#define Tsz 512
#define Dsz 256

// ---- bf16 pack/unpack helpers (weights stored as packed bf16 pairs) ----
__device__ __forceinline__ uint32_t f2bf(float f) {
    uint32_t u = __float_as_uint(f);
    u = (u + 0x7fffu + ((u >> 16) & 1u)) >> 16;   // round-to-nearest-even
    return u & 0xffffu;
}
__device__ __forceinline__ uint32_t packw(float lo, float hi) {
    return f2bf(lo) | (f2bf(hi) << 16);
}
__device__ __forceinline__ float blo(uint32_t u) { return __uint_as_float(u << 16); }
__device__ __forceinline__ float bhi(uint32_t u) { return __uint_as_float(u & 0xffff0000u); }

__device__ __forceinline__ float fsig(float x)  { return 1.0f / (1.0f + __expf(-x)); }
__device__ __forceinline__ float ftanh(float x) { return 2.0f / (1.0f + __expf(-2.0f * x)) - 1.0f; }

// One block = one batch row. 256 threads; thread j owns output column j of the
// big gate matmuls (weights in registers, bf16-packed). GRU weights in LDS.
__global__ __launch_bounds__(256, 2) void rnn_persist(
    const float* __restrict__ pix,
    const float* __restrict__ van_wi, const float* __restrict__ van_bi,
    const float* __restrict__ van_wh, const float* __restrict__ van_bh,
    const float* __restrict__ w1g, const float* __restrict__ b1g,
    const float* __restrict__ w2g, const float* __restrict__ b2g,
    const float* __restrict__ gwi, const float* __restrict__ gwh,
    const float* __restrict__ gb,
    const float* __restrict__ mw1, const float* __restrict__ mb1,
    const float* __restrict__ mw2, const float* __restrict__ mb2,
    const float* __restrict__ mw3, const float* __restrict__ mb3,
    const float* __restrict__ sf,
    float* __restrict__ out)
{
    const int tid = threadIdx.x;
    const int row = blockIdx.x;

    // activations: [h0(0:32) | h1(32:96) | h2(96:160)]
    __shared__ __align__(16) float sAct[160];
    __shared__ __align__(16) float sPix[256];
    __shared__ __align__(16) float sG1[256];
    __shared__ __align__(16) float sG2[256];
    __shared__ __align__(16) float sGG[192];   // z(0:64) r(64:128) a_x(128:192)
    __shared__ __align__(16) float sH3[64];
    __shared__ __align__(16) float sRH3[64];
    __shared__ float sC1[64], sC2[64];
    __shared__ float sVan[8][32];
    __shared__ float sTmp[64];
    __shared__ uint2 sWi2[16][192];            // gru_wi packed: [kq][col] covers k=4kq..4kq+3
    __shared__ uint2 sWh2[16][192];            // gru_wh packed

    // ---- per-thread register weights (bf16 pairs, loaded once) ----
    uint32_t w1r[48];                          // lstm1_w column tid, k=0..95
#pragma unroll
    for (int i = 0; i < 48; ++i)
        w1r[i] = packw(w1g[(2 * i) * 256 + tid], w1g[(2 * i + 1) * 256 + tid]);

    uint32_t w2r[64];                          // lstm2_w column tid, k=0..127
#pragma unroll
    for (int i = 0; i < 64; ++i)
        w2r[i] = packw(w2g[(2 * i) * 256 + tid], w2g[(2 * i + 1) * 256 + tid]);

    const int vc = tid & 31, vs = tid >> 5;    // van: col vc, k-slice vs (8 slices of 32)
    uint32_t wvi[16];
#pragma unroll
    for (int i = 0; i < 16; ++i)
        wvi[i] = packw(van_wi[(32 * vs + 2 * i) * 32 + vc],
                       van_wi[(32 * vs + 2 * i + 1) * 32 + vc]);
    uint32_t wvh[2];
#pragma unroll
    for (int i = 0; i < 2; ++i)
        wvh[i] = packw(van_wh[(4 * vs + 2 * i) * 32 + vc],
                       van_wh[(4 * vs + 2 * i + 1) * 32 + vc]);

    const float b1j = b1g[tid];
    const float b2j = b2g[tid];
    const float gbj = (tid < 192) ? gb[tid] : 0.0f;
    const float vbc = van_bi[vc] + van_bh[vc];

    // gru weights -> LDS (packed, column-major-in-j so lane reads are stride-1)
    for (int idx = tid; idx < 16 * 192; idx += 256) {
        int kq = idx / 192, j = idx - kq * 192;
        uint2 u;
        u.x = packw(gwi[(4 * kq + 0) * 192 + j], gwi[(4 * kq + 1) * 192 + j]);
        u.y = packw(gwi[(4 * kq + 2) * 192 + j], gwi[(4 * kq + 3) * 192 + j]);
        sWi2[kq][j] = u;
        u.x = packw(gwh[(4 * kq + 0) * 192 + j], gwh[(4 * kq + 1) * 192 + j]);
        u.y = packw(gwh[(4 * kq + 2) * 192 + j], gwh[(4 * kq + 3) * 192 + j]);
        sWh2[kq][j] = u;
    }
    if (tid < 160) sAct[tid] = 0.0f;
    if (tid < 64) { sC1[tid] = 0.0f; sC2[tid] = 0.0f; sH3[tid] = 0.0f; }
    float preg = pix[(row * Tsz + 0) * Dsz + tid];   // prefetch t=0
    __syncthreads();

    for (int t = 0; t < Tsz; ++t) {
        sPix[tid] = preg;
        __syncthreads();                                     // B1

        // stage 1: van partials  xw = x@wi + h0@wh  (8-way k-split)
        {
            float acc = 0.0f;
#pragma unroll
            for (int q = 0; q < 8; ++q) {
                float4 a = *(const float4*)&sPix[32 * vs + 4 * q];
                uint32_t ua = wvi[2 * q], ub = wvi[2 * q + 1];
                acc = fmaf(a.x, blo(ua), acc);
                acc = fmaf(a.y, bhi(ua), acc);
                acc = fmaf(a.z, blo(ub), acc);
                acc = fmaf(a.w, bhi(ub), acc);
            }
            {
                float4 a = *(const float4*)&sAct[4 * vs];    // h0 window
                uint32_t ua = wvh[0], ub = wvh[1];
                acc = fmaf(a.x, blo(ua), acc);
                acc = fmaf(a.y, bhi(ua), acc);
                acc = fmaf(a.z, blo(ub), acc);
                acc = fmaf(a.w, bhi(ub), acc);
            }
            sVan[vs][vc] = acc;
        }
        __syncthreads();                                     // B2

        // stage 2: reduce + relu -> h0'
        if (tid < 32) {
            float acc = vbc;
#pragma unroll
            for (int s = 0; s < 8; ++s) acc += sVan[s][tid];
            sAct[tid] = fmaxf(acc, 0.0f);
        }
        __syncthreads();                                     // B3

        if (t + 1 < Tsz) preg = pix[(row * Tsz + (t + 1)) * Dsz + tid];

        // stage 3: lstm1 gates = [h0';h1] @ W1 + b1   (k=96)
        {
            float acc = b1j;
#pragma unroll
            for (int q = 0; q < 24; ++q) {
                float4 a = *(const float4*)&sAct[4 * q];
                uint32_t ua = w1r[2 * q], ub = w1r[2 * q + 1];
                acc = fmaf(a.x, blo(ua), acc);
                acc = fmaf(a.y, bhi(ua), acc);
                acc = fmaf(a.z, blo(ub), acc);
                acc = fmaf(a.w, bhi(ub), acc);
            }
            sG1[tid] = acc;
        }
        __syncthreads();                                     // B4

        // stage 4: lstm1 update
        if (tid < 64) {
            float i = fsig(sG1[tid]);
            float g = ftanh(sG1[64 + tid]);
            float f = fsig(sG1[128 + tid] + 1.0f);
            float o = fsig(sG1[192 + tid]);
            float c = f * sC1[tid] + i * g;
            sC1[tid] = c;
            sAct[32 + tid] = o * ftanh(c);
        }
        __syncthreads();                                     // B5

        // stage 5: lstm2 gates = [h1';h2] @ W2 + b2   (k=128)
        {
            float acc = b2j;
#pragma unroll
            for (int q = 0; q < 32; ++q) {
                float4 a = *(const float4*)&sAct[32 + 4 * q];
                uint32_t ua = w2r[2 * q], ub = w2r[2 * q + 1];
                acc = fmaf(a.x, blo(ua), acc);
                acc = fmaf(a.y, bhi(ua), acc);
                acc = fmaf(a.z, blo(ub), acc);
                acc = fmaf(a.w, bhi(ub), acc);
            }
            sG2[tid] = acc;
        }
        __syncthreads();                                     // B6

        // stage 6: lstm2 update
        if (tid < 64) {
            float i = fsig(sG2[tid]);
            float g = ftanh(sG2[64 + tid]);
            float f = fsig(sG2[128 + tid] + 1.0f);
            float o = fsig(sG2[192 + tid]);
            float c = f * sC2[tid] + i * g;
            sC2[tid] = c;
            sAct[96 + tid] = o * ftanh(c);
        }
        __syncthreads();                                     // B7

        // stage 7: gru gx (192 cols); zr for j<128 (+ rh3 for r-threads)
        if (tid < 192) {
            float acc = 0.0f;
#pragma unroll
            for (int q = 0; q < 16; ++q) {
                float4 a = *(const float4*)&sAct[96 + 4 * q];   // h2'
                uint2 u = sWi2[q][tid];
                acc = fmaf(a.x, blo(u.x), acc);
                acc = fmaf(a.y, bhi(u.x), acc);
                acc = fmaf(a.z, blo(u.y), acc);
                acc = fmaf(a.w, bhi(u.y), acc);
            }
            acc += gbj;
            if (tid < 128) {
                float acc2 = 0.0f;
#pragma unroll
                for (int q = 0; q < 16; ++q) {
                    float4 a = *(const float4*)&sH3[4 * q];
                    uint2 u = sWh2[q][tid];
                    acc2 = fmaf(a.x, blo(u.x), acc2);
                    acc2 = fmaf(a.y, bhi(u.x), acc2);
                    acc2 = fmaf(a.z, blo(u.y), acc2);
                    acc2 = fmaf(a.w, bhi(u.y), acc2);
                }
                float zr = fsig(acc + acc2);
                sGG[tid] = zr;
                if (tid >= 64) sRH3[tid - 64] = zr * sH3[tid - 64];
            } else {
                sGG[tid] = acc;                               // a_x + b_a
            }
        }
        __syncthreads();                                     // B8

        // stage 8: a = tanh(a_x + (r*h3)@Wh_a); h3' = (1-z)h3 + z a
        if (tid < 64) {
            float acc = sGG[128 + tid];
#pragma unroll
            for (int q = 0; q < 16; ++q) {
                float4 a = *(const float4*)&sRH3[4 * q];
                uint2 u = sWh2[q][128 + tid];
                acc = fmaf(a.x, blo(u.x), acc);
                acc = fmaf(a.y, bhi(u.x), acc);
                acc = fmaf(a.z, blo(u.y), acc);
                acc = fmaf(a.w, bhi(u.y), acc);
            }
            float aa = ftanh(acc);
            float z = sGG[tid];
            sH3[tid] = (1.0f - z) * sH3[tid] + z * aa;
        }
        // no barrier needed: next-iteration B1 orders these writes before any reader
    }
    __syncthreads();

    // ---- MLP head (tiny, weights straight from global) ----
    if (tid < 32) {
        float acc = mb1[tid];
#pragma unroll
        for (int k = 0; k < 64; ++k) acc = fmaf(sH3[k], mw1[k * 32 + tid], acc);
        sTmp[tid] = fmaxf(acc, 0.0f);
    }
    __syncthreads();
    if (tid < 32) {
        float acc = mb2[tid];
#pragma unroll
        for (int k = 0; k < 32; ++k) acc = fmaf(sTmp[k], mw2[k * 32 + tid], acc);
        sTmp[32 + tid] = fmaxf(acc, 0.0f);
    }
    __syncthreads();
    if (tid < 12) {
        float acc = mb3[tid];
#pragma unroll
        for (int k = 0; k < 32; ++k) acc = fmaf(sTmp[32 + k], mw3[k * 12 + tid], acc);
        sTmp[tid] = acc;
    }
    __syncthreads();
    if (tid == 0) {
        float acc = 0.0f;
#pragma unroll
        for (int k = 0; k < 12; ++k) acc = fmaf(sTmp[k], sf[k], acc);
        out[24 + row] = acc;            // policy_params[row]
    }
    if (row == 0 && tid < 12) {
        out[tid] = sf[tid];             // successor_features pass-through
        out[12 + tid] = 1.0f;           // preference_vectors (ones)
    }
}

extern "C" void kernel_launch(void* const* d_in, const int* in_sizes, int n_in,
                              void* d_out, int out_size, void* d_ws, size_t ws_size,
                              hipStream_t stream) {
    (void)in_sizes; (void)n_in; (void)d_ws; (void)ws_size; (void)out_size;
    const float* pix    = (const float*)d_in[0];
    const float* van_wi = (const float*)d_in[1];
    const float* van_bi = (const float*)d_in[2];
    const float* van_wh = (const float*)d_in[3];
    const float* van_bh = (const float*)d_in[4];
    const float* w1     = (const float*)d_in[5];
    const float* b1     = (const float*)d_in[6];
    const float* w2     = (const float*)d_in[7];
    const float* b2     = (const float*)d_in[8];
    const float* gwi    = (const float*)d_in[9];
    const float* gwh    = (const float*)d_in[10];
    const float* gb     = (const float*)d_in[11];
    const float* mw1    = (const float*)d_in[12];
    const float* mb1    = (const float*)d_in[13];
    const float* mw2    = (const float*)d_in[14];
    const float* mb2    = (const float*)d_in[15];
    const float* mw3    = (const float*)d_in[16];
    const float* mb3    = (const float*)d_in[17];
    const float* sf     = (const float*)d_in[18];
    float* out = (float*)d_out;

    rnn_persist<<<Bsz, 256, 0, stream>>>(
        pix, van_wi, van_bi, van_wh, van_bh,
        w1, b1, w2, b2, gwi, gwh, gb,
        mw1, mb1, mw2, mb2, mw3, mb3, sf, out);
}

// Round 2
// 981.467 us; speedup vs baseline: 5.9760x; 5.9760x over previous
//
#include <hip/hip_runtime.h>
#include <stdint.h>

#define Bsz 512
#define Tsz 512
#define Dsz 256
#define NCYC (Tsz + 4)   // pipeline depth 5: van t, l1 t-1, l2 t-2, gx t-3, gru t-4

typedef _Float16 h2v __attribute__((ext_vector_type(2)));
union UH { uint32_t u; h2v h; _Float16 s[2]; };

__device__ __forceinline__ uint32_t packh(float a, float b) {
    UH x; x.s[0] = (_Float16)a; x.s[1] = (_Float16)b; return x.u;
}
__device__ __forceinline__ float dot2(uint32_t w, uint32_t a, float acc) {
#if __has_builtin(__builtin_amdgcn_fdot2)
    UH W, A; W.u = w; A.u = a;
    return __builtin_amdgcn_fdot2(W.h, A.h, acc, false);
#else
    UH W, A; W.u = w; A.u = a;
    return acc + (float)W.s[0] * (float)A.s[0] + (float)W.s[1] * (float)A.s[1];
#endif
}
__device__ __forceinline__ float fsig(float x)  { return 1.0f / (1.0f + __expf(-x)); }
__device__ __forceinline__ float ftanh(float x) { return 2.0f / (1.0f + __expf(-2.0f * x)) - 1.0f; }

// Block = one batch row. 448 threads = 7 waves:
//  w0: van (32 units, 2-lane k-split) + pixel prefetch
//  w1-2: lstm1 (128 lanes, 2 gate-cols each, pair-exchange via shfl_xor(1))
//  w3-4: lstm2 (same scheme, k=128)
//  w5: gru gx = h2 @ gru_wi + b (h3-independent, runs one cycle early)
//  w6: gru recurrent part (wave-synchronous internal z,r -> a dependency)
__global__ __launch_bounds__(448) void rnn_pipe(
    const float* __restrict__ pix,
    const float* __restrict__ van_wi, const float* __restrict__ van_bi,
    const float* __restrict__ van_wh, const float* __restrict__ van_bh,
    const float* __restrict__ w1g, const float* __restrict__ b1g,
    const float* __restrict__ w2g, const float* __restrict__ b2g,
    const float* __restrict__ gwi, const float* __restrict__ gwh,
    const float* __restrict__ gb,
    const float* __restrict__ mw1, const float* __restrict__ mb1,
    const float* __restrict__ mw2, const float* __restrict__ mb2,
    const float* __restrict__ mw3, const float* __restrict__ mb3,
    const float* __restrict__ sf,
    float* __restrict__ out)
{
    const int tid  = threadIdx.x;
    const int wv   = tid >> 6;
    const int lane = tid & 63;
    const int row  = blockIdx.x;

    // double-buffered activations (f16)
    __shared__ __align__(16) _Float16 xb [2][256];
    __shared__ __align__(16) _Float16 h0b[2][32];
    __shared__ __align__(16) _Float16 h1b[2][64];
    __shared__ __align__(16) _Float16 h2b[2][64];
    __shared__ __align__(16) _Float16 gxb[2][192];
    // gru-wave private scratch (wave-synchronous use only)
    __shared__ __align__(16) _Float16 h3s[64];
    __shared__ __align__(16) _Float16 rh3s[64];
    __shared__ float sH3f[64];
    __shared__ float sTmp[64];

    // one register-weight array, role-unioned (max user = lstm2: 128 u32)
    uint32_t wreg[128];
    float r0 = 0.f, r1 = 0.f, r2 = 0.f;   // role-specific biases / recurrent state
    float4 pxA{}, pxB{};

    const float* pixrow = pix + (size_t)row * Tsz * Dsz;

    // ---------------- per-role weight load (once) ----------------
    if (wv == 0) {
        const int c = lane & 31, s = lane >> 5;
#pragma unroll
        for (int j = 0; j < 64; ++j)
            wreg[j] = packh(van_wi[(128 * s + 2 * j) * 32 + c],
                            van_wi[(128 * s + 2 * j + 1) * 32 + c]);
#pragma unroll
        for (int j = 0; j < 8; ++j)
            wreg[64 + j] = packh(van_wh[(16 * s + 2 * j) * 32 + c],
                                 van_wh[(16 * s + 2 * j + 1) * 32 + c]);
        r0 = van_bi[c] + van_bh[c];
        // prefetch pipeline for pixels: x(0)->LDS buf1 now, x(1),x(2)->regs
        {
            float4 p0 = *(const float4*)(pixrow + 4 * lane);
            uint32_t* xw = (uint32_t*)xb[1];
            xw[2 * lane]     = packh(p0.x, p0.y);
            xw[2 * lane + 1] = packh(p0.z, p0.w);
            pxA = *(const float4*)(pixrow + (size_t)1 * Dsz + 4 * lane);
            pxB = *(const float4*)(pixrow + (size_t)2 * Dsz + 4 * lane);
        }
    } else if (wv <= 2) {
        const int p = tid - 64, u = p >> 1, odd = p & 1;
        const int c0 = odd ? 128 + u : u;        // even: i_u,g_u; odd: f_u,o_u
        const int c1 = c0 + 64;
#pragma unroll
        for (int j = 0; j < 48; ++j)
            wreg[j] = packh(w1g[(2 * j) * 256 + c0], w1g[(2 * j + 1) * 256 + c0]);
#pragma unroll
        for (int j = 0; j < 48; ++j)
            wreg[48 + j] = packh(w1g[(2 * j) * 256 + c1], w1g[(2 * j + 1) * 256 + c1]);
        r0 = b1g[c0]; r1 = b1g[c1]; r2 = 0.f;    // r2 = c1-state (odd lanes)
    } else if (wv <= 4) {
        const int p = tid - 192, u = p >> 1, odd = p & 1;
        const int c0 = odd ? 128 + u : u;
        const int c1 = c0 + 64;
#pragma unroll
        for (int j = 0; j < 64; ++j)
            wreg[j] = packh(w2g[(2 * j) * 256 + c0], w2g[(2 * j + 1) * 256 + c0]);
#pragma unroll
        for (int j = 0; j < 64; ++j)
            wreg[64 + j] = packh(w2g[(2 * j) * 256 + c1], w2g[(2 * j + 1) * 256 + c1]);
        r0 = b1g ? b2g[c0] : 0.f; r1 = b2g[c1]; r2 = 0.f;
    } else if (wv == 5) {
        const int l = lane;
#pragma unroll
        for (int j = 0; j < 32; ++j) {
            wreg[j]      = packh(gwi[(2 * j) * 192 + l],       gwi[(2 * j + 1) * 192 + l]);
            wreg[32 + j] = packh(gwi[(2 * j) * 192 + 64 + l],  gwi[(2 * j + 1) * 192 + 64 + l]);
            wreg[64 + j] = packh(gwi[(2 * j) * 192 + 128 + l], gwi[(2 * j + 1) * 192 + 128 + l]);
        }
        r0 = gb[l]; r1 = gb[64 + l]; r2 = gb[128 + l];
    } else {
        const int l = lane;
#pragma unroll
        for (int j = 0; j < 32; ++j) {
            wreg[j]      = packh(gwh[(2 * j) * 192 + l],       gwh[(2 * j + 1) * 192 + l]);
            wreg[32 + j] = packh(gwh[(2 * j) * 192 + 64 + l],  gwh[(2 * j + 1) * 192 + 64 + l]);
            wreg[64 + j] = packh(gwh[(2 * j) * 192 + 128 + l], gwh[(2 * j + 1) * 192 + 128 + l]);
        }
        r0 = 0.f;                                // r0 = h3 state (f32)
    }

    // zero-init state buffers (both phases)
    for (int i = tid; i < 2 * 32; i += 448)  ((_Float16*)h0b)[i] = (_Float16)0.f;
    for (int i = tid; i < 2 * 64; i += 448)  ((_Float16*)h1b)[i] = (_Float16)0.f;
    for (int i = tid; i < 2 * 64; i += 448)  ((_Float16*)h2b)[i] = (_Float16)0.f;
    for (int i = tid; i < 2 * 192; i += 448) ((_Float16*)gxb)[i] = (_Float16)0.f;
    for (int i = tid; i < 64; i += 448)      { h3s[i] = (_Float16)0.f; rh3s[i] = (_Float16)0.f; }
    __syncthreads();

    // ---------------- pipelined recurrence ----------------
    for (int n = 0; n < NCYC; ++n) {
        const int wb = n & 1, rb = (n + 1) & 1;

        if (wv == 0) {
            // store x(n+1) (held in pxA), advance prefetch
            if (n + 1 < Tsz) {
                uint32_t* xw = (uint32_t*)xb[wb];
                xw[2 * lane]     = packh(pxA.x, pxA.y);
                xw[2 * lane + 1] = packh(pxA.z, pxA.w);
            }
            pxA = pxB;
            if (n + 3 < Tsz)
                pxB = *(const float4*)(pixrow + (size_t)(n + 3) * Dsz + 4 * lane);
            if (n < Tsz) {
                const int c = lane & 31, s = lane >> 5;
                const uint4* xq = (const uint4*)xb[rb];
                const uint4* hq = (const uint4*)h0b[rb];
                float a0 = 0.f, a1 = 0.f;
#pragma unroll
                for (int q = 0; q < 16; ++q) {
                    uint4 v = xq[16 * s + q];
                    a0 = dot2(wreg[4 * q + 0], v.x, a0);
                    a1 = dot2(wreg[4 * q + 1], v.y, a1);
                    a0 = dot2(wreg[4 * q + 2], v.z, a0);
                    a1 = dot2(wreg[4 * q + 3], v.w, a1);
                }
#pragma unroll
                for (int q = 0; q < 2; ++q) {
                    uint4 v = hq[2 * s + q];
                    a0 = dot2(wreg[64 + 4 * q + 0], v.x, a0);
                    a1 = dot2(wreg[64 + 4 * q + 1], v.y, a1);
                    a0 = dot2(wreg[64 + 4 * q + 2], v.z, a0);
                    a1 = dot2(wreg[64 + 4 * q + 3], v.w, a1);
                }
                float acc = a0 + a1;
                acc += __shfl_xor(acc, 32);
                if (s == 0) h0b[wb][c] = (_Float16)fmaxf(acc + r0, 0.f);
            }
        } else if (wv <= 2) {
            const int t = n - 1;
            if (0 <= t && t < Tsz) {
                const int p = tid - 64, u = p >> 1, odd = p & 1;
                const uint4* aq = (const uint4*)h0b[rb];   // 4 uint4
                const uint4* bq = (const uint4*)h1b[rb];   // 8 uint4
                float a0 = r0, a1 = r1, x0 = 0.f, x1 = 0.f;
#pragma unroll
                for (int q = 0; q < 4; ++q) {
                    uint4 v = aq[q];
                    a0 = dot2(wreg[4 * q + 0], v.x, a0);
                    x0 = dot2(wreg[4 * q + 1], v.y, x0);
                    a0 = dot2(wreg[4 * q + 2], v.z, a0);
                    x0 = dot2(wreg[4 * q + 3], v.w, x0);
                    a1 = dot2(wreg[48 + 4 * q + 0], v.x, a1);
                    x1 = dot2(wreg[48 + 4 * q + 1], v.y, x1);
                    a1 = dot2(wreg[48 + 4 * q + 2], v.z, a1);
                    x1 = dot2(wreg[48 + 4 * q + 3], v.w, x1);
                }
#pragma unroll
                for (int q = 0; q < 8; ++q) {
                    uint4 v = bq[q];
                    a0 = dot2(wreg[16 + 4 * q + 0], v.x, a0);
                    x0 = dot2(wreg[16 + 4 * q + 1], v.y, x0);
                    a0 = dot2(wreg[16 + 4 * q + 2], v.z, a0);
                    x0 = dot2(wreg[16 + 4 * q + 3], v.w, x0);
                    a1 = dot2(wreg[64 + 4 * q + 0], v.x, a1);
                    x1 = dot2(wreg[64 + 4 * q + 1], v.y, x1);
                    a1 = dot2(wreg[64 + 4 * q + 2], v.z, a1);
                    x1 = dot2(wreg[64 + 4 * q + 3], v.w, x1);
                }
                float g0 = a0 + x0, g1 = a1 + x1;
                float send = 0.f, fq = 0.f, op = 0.f;
                if (!odd) send = fsig(g0) * ftanh(g1);      // sig(i)*tanh(g)
                else { fq = fsig(g0 + 1.f); op = fsig(g1); }
                float pr = __shfl_xor(send, 1);
                if (odd) {
                    r2 = fq * r2 + pr;
                    h1b[wb][u] = (_Float16)(op * ftanh(r2));
                }
            }
        } else if (wv <= 4) {
            const int t = n - 2;
            if (0 <= t && t < Tsz) {
                const int p = tid - 192, u = p >> 1, odd = p & 1;
                const uint4* aq = (const uint4*)h1b[rb];   // 8 uint4
                const uint4* bq = (const uint4*)h2b[rb];   // 8 uint4
                float a0 = r0, a1 = r1, x0 = 0.f, x1 = 0.f;
#pragma unroll
                for (int q = 0; q < 8; ++q) {
                    uint4 v = aq[q];
                    a0 = dot2(wreg[4 * q + 0], v.x, a0);
                    x0 = dot2(wreg[4 * q + 1], v.y, x0);
                    a0 = dot2(wreg[4 * q + 2], v.z, a0);
                    x0 = dot2(wreg[4 * q + 3], v.w, x0);
                    a1 = dot2(wreg[64 + 4 * q + 0], v.x, a1);
                    x1 = dot2(wreg[64 + 4 * q + 1], v.y, x1);
                    a1 = dot2(wreg[64 + 4 * q + 2], v.z, a1);
                    x1 = dot2(wreg[64 + 4 * q + 3], v.w, x1);
                }
#pragma unroll
                for (int q = 0; q < 8; ++q) {
                    uint4 v = bq[q];
                    a0 = dot2(wreg[32 + 4 * q + 0], v.x, a0);
                    x0 = dot2(wreg[32 + 4 * q + 1], v.y, x0);
                    a0 = dot2(wreg[32 + 4 * q + 2], v.z, a0);
                    x0 = dot2(wreg[32 + 4 * q + 3], v.w, x0);
                    a1 = dot2(wreg[96 + 4 * q + 0], v.x, a1);
                    x1 = dot2(wreg[96 + 4 * q + 1], v.y, x1);
                    a1 = dot2(wreg[96 + 4 * q + 2], v.z, a1);
                    x1 = dot2(wreg[96 + 4 * q + 3], v.w, x1);
                }
                float g0 = a0 + x0, g1 = a1 + x1;
                float send = 0.f, fq = 0.f, op = 0.f;
                if (!odd) send = fsig(g0) * ftanh(g1);
                else { fq = fsig(g0 + 1.f); op = fsig(g1); }
                float pr = __shfl_xor(send, 1);
                if (odd) {
                    r2 = fq * r2 + pr;
                    h2b[wb][u] = (_Float16)(op * ftanh(r2));
                }
            }
        } else if (wv == 5) {
            const int t = n - 3;
            if (0 <= t && t < Tsz) {
                const uint4* hq = (const uint4*)h2b[rb];   // 8 uint4
                float az = r0, ar = r1, aa = r2;
#pragma unroll
                for (int q = 0; q < 8; ++q) {
                    uint4 v = hq[q];
                    az = dot2(wreg[4 * q + 0], v.x, az);
                    az = dot2(wreg[4 * q + 1], v.y, az);
                    az = dot2(wreg[4 * q + 2], v.z, az);
                    az = dot2(wreg[4 * q + 3], v.w, az);
                    ar = dot2(wreg[32 + 4 * q + 0], v.x, ar);
                    ar = dot2(wreg[32 + 4 * q + 1], v.y, ar);
                    ar = dot2(wreg[32 + 4 * q + 2], v.z, ar);
                    ar = dot2(wreg[32 + 4 * q + 3], v.w, ar);
                    aa = dot2(wreg[64 + 4 * q + 0], v.x, aa);
                    aa = dot2(wreg[64 + 4 * q + 1], v.y, aa);
                    aa = dot2(wreg[64 + 4 * q + 2], v.z, aa);
                    aa = dot2(wreg[64 + 4 * q + 3], v.w, aa);
                }
                gxb[wb][lane]       = (_Float16)az;
                gxb[wb][64 + lane]  = (_Float16)ar;
                gxb[wb][128 + lane] = (_Float16)aa;
            }
        } else {
            const int t = n - 4;
            if (0 <= t && t < Tsz) {
                const int l = lane;
                float gz = (float)gxb[rb][l];
                float gr = (float)gxb[rb][64 + l];
                float ga = (float)gxb[rb][128 + l];
                const uint4* hq = (const uint4*)h3s;       // h3(t-1), 8 uint4
                float az = gz, ar = gr;
#pragma unroll
                for (int q = 0; q < 8; ++q) {
                    uint4 v = hq[q];
                    az = dot2(wreg[4 * q + 0], v.x, az);
                    az = dot2(wreg[4 * q + 1], v.y, az);
                    az = dot2(wreg[4 * q + 2], v.z, az);
                    az = dot2(wreg[4 * q + 3], v.w, az);
                    ar = dot2(wreg[32 + 4 * q + 0], v.x, ar);
                    ar = dot2(wreg[32 + 4 * q + 1], v.y, ar);
                    ar = dot2(wreg[32 + 4 * q + 2], v.z, ar);
                    ar = dot2(wreg[32 + 4 * q + 3], v.w, ar);
                }
                float z = fsig(az), r = fsig(ar);
                rh3s[l] = (_Float16)(r * r0);
                asm volatile("s_waitcnt lgkmcnt(0)" ::: "memory");   // wave-sync LDS
                const uint4* rq = (const uint4*)rh3s;
                float aa = ga, ab = 0.f;
#pragma unroll
                for (int q = 0; q < 8; ++q) {
                    uint4 v = rq[q];
                    aa = dot2(wreg[64 + 4 * q + 0], v.x, aa);
                    ab = dot2(wreg[64 + 4 * q + 1], v.y, ab);
                    aa = dot2(wreg[64 + 4 * q + 2], v.z, aa);
                    ab = dot2(wreg[64 + 4 * q + 3], v.w, ab);
                }
                float a = ftanh(aa + ab);
                r0 = (1.f - z) * r0 + z * a;
                h3s[l] = (_Float16)r0;                     // for next gru cycle
            }
        }
        __syncthreads();
    }

    // ---------------- MLP head ----------------
    if (wv == 6) sH3f[lane] = r0;
    __syncthreads();
    if (tid < 32) {
        float acc = mb1[tid];
#pragma unroll
        for (int k = 0; k < 64; ++k) acc = fmaf(sH3f[k], mw1[k * 32 + tid], acc);
        sTmp[tid] = fmaxf(acc, 0.0f);
    }
    __syncthreads();
    if (tid < 32) {
        float acc = mb2[tid];
#pragma unroll
        for (int k = 0; k < 32; ++k) acc = fmaf(sTmp[k], mw2[k * 32 + tid], acc);
        sTmp[32 + tid] = fmaxf(acc, 0.0f);
    }
    __syncthreads();
    if (tid < 12) {
        float acc = mb3[tid];
#pragma unroll
        for (int k = 0; k < 32; ++k) acc = fmaf(sTmp[32 + k], mw3[k * 12 + tid], acc);
        sTmp[tid] = acc;
    }
    __syncthreads();
    if (tid == 0) {
        float acc = 0.0f;
#pragma unroll
        for (int k = 0; k < 12; ++k) acc = fmaf(sTmp[k], sf[k], acc);
        out[24 + row] = acc;
    }
    if (row == 0 && tid < 12) {
        out[tid] = sf[tid];
        out[12 + tid] = 1.0f;
    }
}

extern "C" void kernel_launch(void* const* d_in, const int* in_sizes, int n_in,
                              void* d_out, int out_size, void* d_ws, size_t ws_size,
                              hipStream_t stream) {
    (void)in_sizes; (void)n_in; (void)d_ws; (void)ws_size; (void)out_size;
    const float* pix    = (const float*)d_in[0];
    const float* van_wi = (const float*)d_in[1];
    const float* van_bi = (const float*)d_in[2];
    const float* van_wh = (const float*)d_in[3];
    const float* van_bh = (const float*)d_in[4];
    const float* w1     = (const float*)d_in[5];
    const float* b1     = (const float*)d_in[6];
    const float* w2     = (const float*)d_in[7];
    const float* b2     = (const float*)d_in[8];
    const float* gwi    = (const float*)d_in[9];
    const float* gwh    = (const float*)d_in[10];
    const float* gb     = (const float*)d_in[11];
    const float* mw1    = (const float*)d_in[12];
    const float* mb1    = (const float*)d_in[13];
    const float* mw2    = (const float*)d_in[14];
    const float* mb2    = (const float*)d_in[15];
    const float* mw3    = (const float*)d_in[16];
    const float* mb3    = (const float*)d_in[17];
    const float* sf     = (const float*)d_in[18];
    float* out = (float*)d_out;

    rnn_pipe<<<Bsz, 448, 0, stream>>>(
        pix, van_wi, van_bi, van_wh, van_bh,
        w1, b1, w2, b2, gwi, gwh, gb,
        mw1, mb1, mw2, mb2, mw3, mb3, sf, out);
}